// Round 2
// baseline (73.799 us; speedup 1.0000x reference)
//
#include <hip/hip_runtime.h>

// CORN loss: logits [B, K-1] fp32, targets [B] int (1..K), out = mean loss (fp32 scalar)
// B = 4194304, K = 10 -> 9 logits/row, 37.7M loss terms.
// loss(x, bt) = -log(sigmoid(bt ? x : -x) + 1e-7) ~= log(1 + exp(bt ? -x : x))
// (eps bias <= ~3e-5 on the mean; threshold is 1.6e-2)

#define BATCH    4194304
#define KM1      9

constexpr int BLOCKS  = 4096;
constexpr int THREADS = 256;
// BLOCKS*THREADS == BATCH/4 == 1048576 groups of 4 rows, exactly 1 per thread.

typedef __attribute__((ext_vector_type(4))) float f32x4;

__global__ __launch_bounds__(THREADS, 4) void corn_partial_kernel(
    const float* __restrict__ logits,
    const int*   __restrict__ targets,
    float*       __restrict__ partials) {
    const int tid  = blockIdx.x * THREADS + threadIdx.x;
    const int row0 = tid * 4;

    // 4 targets, 16B-aligned
    const int4 t4 = *reinterpret_cast<const int4*>(targets + row0);

    // 4 rows * 9 logits = 36 floats = 9 float4, byte offset 144*tid -> 16B aligned.
    // All loads issued up-front (10-deep MLP per thread), nontemporal (read-once).
    const f32x4* src = reinterpret_cast<const f32x4*>(logits + (size_t)row0 * KM1);
    f32x4 v[9];
    #pragma unroll
    for (int i = 0; i < 9; ++i) v[i] = __builtin_nontemporal_load(src + i);

    const int rank[4] = { t4.x - 1, t4.y - 1, t4.z - 1, t4.w - 1 };
    const float* f = reinterpret_cast<const float*>(v);  // compile-time indexing only

    float acc = 0.0f;
    #pragma unroll
    for (int r = 0; r < 4; ++r) {
        const int rk = rank[r];
        #pragma unroll
        for (int k = 0; k < 9; ++k) {
            const float x = f[r * 9 + k];
            const float s = (k < rk) ? -x : x;     // bt=1 -> exp(-x), bt=0 -> exp(x)
            acc += __logf(1.0f + __expf(s));       // softplus: 2 trans + ~4 VALU
        }
    }

    // wave (64-lane) butterfly reduce
    #pragma unroll
    for (int off = 32; off > 0; off >>= 1)
        acc += __shfl_down(acc, off, 64);

    __shared__ float smem[THREADS / 64];
    if ((threadIdx.x & 63) == 0) smem[threadIdx.x >> 6] = acc;
    __syncthreads();
    if (threadIdx.x == 0) {
        partials[blockIdx.x] = smem[0] + smem[1] + smem[2] + smem[3];
    }
}

__global__ __launch_bounds__(256) void corn_final_kernel(
    const float* __restrict__ partials,
    float*       __restrict__ out) {
    float acc = 0.0f;
    #pragma unroll
    for (int i = 0; i < BLOCKS / 256; ++i)
        acc += partials[i * 256 + threadIdx.x];

    #pragma unroll
    for (int off = 32; off > 0; off >>= 1)
        acc += __shfl_down(acc, off, 64);

    __shared__ float smem[4];
    if ((threadIdx.x & 63) == 0) smem[threadIdx.x >> 6] = acc;
    __syncthreads();
    if (threadIdx.x == 0) {
        const float inv_n = 1.0f / (float)(BATCH * KM1);
        out[0] = (smem[0] + smem[1] + smem[2] + smem[3]) * inv_n;
    }
}

extern "C" void kernel_launch(void* const* d_in, const int* in_sizes, int n_in,
                              void* d_out, int out_size, void* d_ws, size_t ws_size,
                              hipStream_t stream) {
    const float* logits   = (const float*)d_in[0];
    const int*   targets  = (const int*)d_in[1];
    float*       out      = (float*)d_out;
    float*       partials = (float*)d_ws;  // 4096 floats = 16 KB scratch

    corn_partial_kernel<<<BLOCKS, THREADS, 0, stream>>>(logits, targets, partials);
    corn_final_kernel<<<1, 256, 0, stream>>>(partials, out);
}

// Round 3
// 33.569 us; speedup vs baseline: 2.1984x; 2.1984x over previous
//
#include <hip/hip_runtime.h>

// CORN loss: logits [B, K-1] fp32, targets [B] int (1..K), out = mean loss (fp32 scalar)
// B = 4194304, K = 10 -> 9 logits/row, 37,748,736 loss terms = 9,437,184 float4s.
// loss(x, bt) = -log(sigmoid(bt ? x : -x) + 1e-7) ~= log(1 + exp(bt ? -x : x))
//
// Layout: fully coalesced logits loads (lane stride 16 B). Each thread owns 4
// float4s at wave stride; row/k derived per float4 via magic div-by-9 (a float4
// spans at most 2 consecutive rows). Target reads are L1-served (~456 B span
// per wave instruction).

#define BATCH    4194304
#define KM1      9

constexpr int THREADS = 256;
constexpr int F4_PER_THREAD = 4;
constexpr int BLOCKS = (BATCH * KM1 / 4) / (THREADS * F4_PER_THREAD);  // 9216

typedef __attribute__((ext_vector_type(4))) float f32x4;

__global__ __launch_bounds__(THREADS) void corn_partial_kernel(
    const float* __restrict__ logits,
    const int*   __restrict__ targets,
    float*       __restrict__ partials) {
    const unsigned q0 = blockIdx.x * (THREADS * F4_PER_THREAD) + threadIdx.x;

    // Issue all 4 coalesced logits loads up-front (instruction j: lane-contiguous 4 KB)
    f32x4 v[F4_PER_THREAD];
    #pragma unroll
    for (int j = 0; j < F4_PER_THREAD; ++j)
        v[j] = reinterpret_cast<const f32x4*>(logits)[q0 + j * THREADS];

    // Per-float4 row/rank bookkeeping (targets via L1)
    int rk0[F4_PER_THREAD], rk1[F4_PER_THREAD], kk0[F4_PER_THREAD];
    #pragma unroll
    for (int j = 0; j < F4_PER_THREAD; ++j) {
        const unsigned e0  = (q0 + j * THREADS) * 4u;   // first element index
        const unsigned row = e0 / 9u;                   // magic-mul div
        kk0[j] = (int)(e0 - 9u * row);
        const unsigned r1 = (row + 1u < BATCH) ? row + 1u : (BATCH - 1u);
        rk0[j] = targets[row] - 1;
        rk1[j] = targets[r1]  - 1;
    }

    float acc = 0.0f;
    #pragma unroll
    for (int j = 0; j < F4_PER_THREAD; ++j) {
        const float* f = reinterpret_cast<const float*>(&v[j]);
        #pragma unroll
        for (int c = 0; c < 4; ++c) {
            const int k      = kk0[j] + c;
            const bool nextr = (k >= 9);
            const int  kk    = nextr ? k - 9 : k;
            const int  rk    = nextr ? rk1[j] : rk0[j];
            const float x = f[c];
            const float s = (kk < rk) ? -x : x;   // bt=1 -> exp(-x), bt=0 -> exp(x)
            acc += __logf(1.0f + __expf(s));      // softplus
        }
    }

    // wave (64-lane) butterfly reduce
    #pragma unroll
    for (int off = 32; off > 0; off >>= 1)
        acc += __shfl_down(acc, off, 64);

    __shared__ float smem[THREADS / 64];
    if ((threadIdx.x & 63) == 0) smem[threadIdx.x >> 6] = acc;
    __syncthreads();
    if (threadIdx.x == 0)
        partials[blockIdx.x] = smem[0] + smem[1] + smem[2] + smem[3];
}

__global__ __launch_bounds__(256) void corn_final_kernel(
    const float* __restrict__ partials,
    float*       __restrict__ out) {
    float acc = 0.0f;
    #pragma unroll
    for (int i = 0; i < BLOCKS / 256; ++i)       // 36 coalesced reads/thread
        acc += partials[i * 256 + threadIdx.x];

    #pragma unroll
    for (int off = 32; off > 0; off >>= 1)
        acc += __shfl_down(acc, off, 64);

    __shared__ float smem[4];
    if ((threadIdx.x & 63) == 0) smem[threadIdx.x >> 6] = acc;
    __syncthreads();
    if (threadIdx.x == 0) {
        const float inv_n = 1.0f / (float)(BATCH * KM1);
        out[0] = (smem[0] + smem[1] + smem[2] + smem[3]) * inv_n;
    }
}

extern "C" void kernel_launch(void* const* d_in, const int* in_sizes, int n_in,
                              void* d_out, int out_size, void* d_ws, size_t ws_size,
                              hipStream_t stream) {
    const float* logits   = (const float*)d_in[0];
    const int*   targets  = (const int*)d_in[1];
    float*       out      = (float*)d_out;
    float*       partials = (float*)d_ws;  // 9216 floats = 36 KB scratch

    corn_partial_kernel<<<BLOCKS, THREADS, 0, stream>>>(logits, targets, partials);
    corn_final_kernel<<<1, 256, 0, stream>>>(partials, out);
}